// Round 19
// baseline (508.837 us; speedup 1.0000x reference)
//
#include <hip/hip_runtime.h>
#include <hip/hip_bf16.h>

// ---------------- problem constants ----------------
#define NB   256        // batch
#define NT   205        // tokens per batch (1 CLS + 196 patches + 8 concept)
#define DIMD 768
#define NCC  8
#define NPP  196
#define LDY  1536       // yv row stride (Y | V concatenated)
#define SCL  0.03608439182435161f   // 768^-0.5

using u16 = unsigned short;
using u32 = unsigned int;
using bf16x8 = __attribute__((ext_vector_type(8))) short;
using f32x4  = __attribute__((ext_vector_type(4))) float;

// ---------------- buffer byte offsets ----------------
// d_ws:  wb[1536x768 bf16] | yv[52480x1536 bf16] | pb[52480x256 bf16]
//   wb:  [0, 2359296)   yv: [3538944, 164757504)   pb: [164757504, 191627264) < safe 245366784.
#define WS_WB   0ul
#define WS_YV   3538944ul
#define WS_PB   164757504ul
// d_out: [0,43033600) = attn fp32 (final, k_sms). [43033600,204129280) = out fp32 (final, k_pv).
//        Temporaries in the tail (all dead before k_pv writes):
//          xb bf16 x [52480x768]  (live until k_sms)      @ +43033600  (ends 123,642,880)
//          Mt fp32 [768x768] = Wk^T*Wq = M^T              @ +143696896
//          zz fp32 [2048x768]                             @ +149988352
//          regm fp32 [2048x196] masked region values      @ +157885440 (ends 159,491,072)
#define DO_OUT  43033600ul
#define DO_XB   43033600ul
#define DO_M    143696896ul
#define DO_Z    149988352ul
#define DO_REGM 157885440ul

__device__ __forceinline__ u16 f2bf(float f) {
  u32 u = __float_as_uint(f);
  u += 0x7FFFu + ((u >> 16) & 1u);
  return (u16)(u >> 16);
}

__device__ __forceinline__ void gld16(const void* g, void* l) {
  __builtin_amdgcn_global_load_lds((const __attribute__((address_space(1))) u32*)g,
                                   (__attribute__((address_space(3))) u32*)l, 16, 0, 0);
}

__device__ __forceinline__ f32x4 mfma16(bf16x8 a, bf16x8 b, f32x4 c) {
  return __builtin_amdgcn_mfma_f32_16x16x32_bf16(a, b, c, 0, 0, 0);
}

// ---------------- device fn: fp32 -> bf16 cast body, 8 elems per slot ----------------
__device__ __forceinline__ void dev_cast(const float* __restrict__ s, u16* __restrict__ d, int i, int n8) {
  if (i >= n8) return;
  const float4* s4 = (const float4*)s;
  float4 a = s4[2*(size_t)i], b = s4[2*(size_t)i + 1];
  union { u16 h[8]; uint4 v; } r;
  r.h[0]=f2bf(a.x); r.h[1]=f2bf(a.y); r.h[2]=f2bf(a.z); r.h[3]=f2bf(a.w);
  r.h[4]=f2bf(b.x); r.h[5]=f2bf(b.y); r.h[6]=f2bf(b.z); r.h[7]=f2bf(b.w);
  *(uint4*)(d + 8*(size_t)i) = r.v;
}

// ---------------- device fn: fp32 tiled GEMM (64x64 tile, 4x4/thread) ----------------
// AM: 0 = A [M,K]; 1 = A [K,M] (transposed); 2 = [M,K] with concept-row gather.
// BT: B [N,K] if true else [K,N].  CB: also emit bf16 copy of C into Cb.
template<int AM, bool BT, bool CB>
__device__ void dev_gemm32(const float* __restrict__ A, const float* __restrict__ Bm,
                           float* __restrict__ C, u16* __restrict__ Cb,
                           int lda, int ldb, int ldc, int K, int nbn, int bid) {
  __shared__ float As[16][68];
  __shared__ float Bs[16][68];
  const int tid = threadIdx.x;
  const int m0 = (bid / nbn) * 64, n0 = (bid % nbn) * 64;
  const int ty = tid >> 4, tx = tid & 15;
  const int sr = tid >> 2, sk = (tid & 3) * 4;
  float acc[4][4] = {};
  for (int k0 = 0; k0 < K; k0 += 16) {
    if (AM == 1) {
      const int ak = tid >> 4, am = (tid & 15) * 4;
      float4 av = *(const float4*)&A[(size_t)(k0 + ak) * lda + m0 + am];
      *(float4*)&As[ak][am] = av;
    } else {
      size_t arow = (size_t)(m0 + sr);
      if (AM == 2) arow = (arow >> 3) * 205 + 197 + (arow & 7);
      float4 av = *(const float4*)&A[arow * lda + k0 + sk];
      As[sk+0][sr] = av.x; As[sk+1][sr] = av.y; As[sk+2][sr] = av.z; As[sk+3][sr] = av.w;
    }
    if (BT) {
      float4 bv = *(const float4*)&Bm[(size_t)(n0 + sr) * ldb + k0 + sk];
      Bs[sk+0][sr] = bv.x; Bs[sk+1][sr] = bv.y; Bs[sk+2][sr] = bv.z; Bs[sk+3][sr] = bv.w;
    } else {
      const int bk = tid >> 4, bn4 = (tid & 15) * 4;
      float4 bv = *(const float4*)&Bm[(size_t)(k0 + bk) * ldb + n0 + bn4];
      *(float4*)&Bs[bk][bn4] = bv;
    }
    __syncthreads();
    #pragma unroll
    for (int kk = 0; kk < 16; ++kk) {
      float4 a4 = *(const float4*)&As[kk][ty*4];
      float4 b4 = *(const float4*)&Bs[kk][tx*4];
      float a[4] = {a4.x, a4.y, a4.z, a4.w};
      float b[4] = {b4.x, b4.y, b4.z, b4.w};
      #pragma unroll
      for (int i = 0; i < 4; ++i)
        #pragma unroll
        for (int j = 0; j < 4; ++j) acc[i][j] += a[i]*b[j];
    }
    __syncthreads();
  }
  #pragma unroll
  for (int i = 0; i < 4; ++i) {
    float4 o = {acc[i][0], acc[i][1], acc[i][2], acc[i][3]};
    *(float4*)&C[(size_t)(m0 + ty*4 + i) * ldc + n0 + tx*4] = o;
    if (CB) {
      union { u16 h[4]; uint2 v; } w;
      w.h[0] = f2bf(o.x); w.h[1] = f2bf(o.y); w.h[2] = f2bf(o.z); w.h[3] = f2bf(o.w);
      *(uint2*)&Cb[(size_t)(m0 + ty*4 + i) * ldc + n0 + tx*4] = w.v;
    }
  }
}

// ---------------- fused launch 1: blocks [0,144) = Mt GEMM (+bf16 copy); rest = casts -------------
#define NGX 5038080   // x groups of 8
#define NGW 73728     // Wv groups of 8
__global__ __launch_bounds__(256) void k_L1(const float* __restrict__ Wk, const float* __restrict__ Wq,
                                            float* __restrict__ Mt, u16* __restrict__ wb,
                                            const float* __restrict__ x, u16* __restrict__ xb,
                                            const float* __restrict__ wv, u16* __restrict__ wbv) {
  const int bid = blockIdx.x;
  if (bid < 144) {
    dev_gemm32<1, false, true>(Wk, Wq, Mt, wb, 768, 768, 768, 768, 12, bid);
  } else {
    int i = (bid - 144) * 256 + threadIdx.x;
    if (i < NGX) dev_cast(x, xb, i, NGX);
    else dev_cast(wv, wbv, i - NGX, NGW);
  }
}

// ---------------- standalone zz GEMM (round-12 lesson: never fuse into the MFMA kernel) -----------
__global__ __launch_bounds__(256) void k_zz(const float* __restrict__ x, const float* __restrict__ Mt,
                                            float* __restrict__ zz) {
  dev_gemm32<2, true, false>(x, Mt, zz, nullptr, 768, 768, 768, 768, 12, blockIdx.x);
}

// ---------------- big Y|V GEMM: round-6 form, byte-identical (measured 8x at 188-192us, VGPR 68).
// Structural-change log: epilogue-staging (r7, +170us), kernel fusion (r12, +60us), dbuf
// issue-early (r14, +15us). DO NOT MODIFY.
__global__ __launch_bounds__(256) void k_yv(const u16* __restrict__ A, const u16* __restrict__ Bt, u16* __restrict__ C) {
  __shared__ u16 As[128*32];
  __shared__ u16 Bs[128*32];
  const int tid = threadIdx.x, wid = tid >> 6, lane = tid & 63;
  const int swz = (blockIdx.x & 7) * 615 + (blockIdx.x >> 3);
  const int bm = swz / 12, bn = swz % 12;
  const size_t m0 = (size_t)bm * 128;
  const int n0 = bn * 128;
  const int wr = (wid >> 1) * 64, wc = (wid & 1) * 64;
  const int fr = lane & 15, fg = lane >> 4;
  const int eb0 = (wid*2+0)*512, eb1 = (wid*2+1)*512;
  const int e0 = eb0 + lane*8, e1 = eb1 + lane*8;
  const int r0 = e0 >> 5, c0 = e0 & 31, r1 = e1 >> 5, c1 = e1 & 31;
  f32x4 acc[4][4] = {};
  for (int k0 = 0; k0 < 768; k0 += 32) {
    gld16(A + (m0 + r0)*768 + k0 + c0, (char*)As + 2*eb0);
    gld16(A + (m0 + r1)*768 + k0 + c1, (char*)As + 2*eb1);
    gld16(Bt + (size_t)(n0 + r0)*768 + k0 + c0, (char*)Bs + 2*eb0);
    gld16(Bt + (size_t)(n0 + r1)*768 + k0 + c1, (char*)Bs + 2*eb1);
    __syncthreads();
    bf16x8 av[4], bv[4];
    #pragma unroll
    for (int m = 0; m < 4; ++m) av[m] = *(const bf16x8*)&As[(wr + m*16 + fr)*32 + fg*8];
    #pragma unroll
    for (int n = 0; n < 4; ++n) bv[n] = *(const bf16x8*)&Bs[(wc + n*16 + fr)*32 + fg*8];
    #pragma unroll
    for (int m = 0; m < 4; ++m)
      #pragma unroll
      for (int n = 0; n < 4; ++n)
        acc[m][n] = mfma16(av[m], bv[n], acc[m][n]);
    __syncthreads();
  }
  #pragma unroll
  for (int m = 0; m < 4; ++m) {
    #pragma unroll
    for (int j = 0; j < 4; ++j) {
      size_t row = m0 + wr + m*16 + fg*4 + j;
      u16* cp = C + row*LDY + n0 + wc;
      #pragma unroll
      for (int n = 0; n < 4; ++n) cp[n*16 + fr] = f2bf(acc[m][n][j]);
    }
  }
}

// ---------------- fused region + argmax + gaussian mask v2: TWO blocks per batch ------------------
// Parallelization split (same values as v1): block (b, half) computes concept rows half*4..half*4+3.
// Per-thread dot work halved; zs load halved; 2 blocks/CU.
__global__ __launch_bounds__(256) void k_regmask(const float* __restrict__ zz, const float* __restrict__ x,
                                                 float* __restrict__ regm) {
  const int b = blockIdx.x >> 1, half = blockIdx.x & 1, tid = threadIdx.x;
  __shared__ float zs[4*768];   // 12 KB
  __shared__ float rs[4*NPP];   // 3.1 KB
  for (int idx = tid; idx < 4*768; idx += 256)
    zs[idx] = zz[((size_t)b*8 + half*4) * 768 + idx];
  __syncthreads();
  if (tid < NPP) {
    const float* xp = x + ((size_t)b*NT + 1 + tid) * DIMD;
    float a0=0, a1=0, a2=0, a3=0;
    #pragma unroll 4
    for (int d = 0; d < 768; d += 4) {
      float4 xv = *(const float4*)&xp[d];
      a0 += zs[0*768+d]*xv.x + zs[0*768+d+1]*xv.y + zs[0*768+d+2]*xv.z + zs[0*768+d+3]*xv.w;
      a1 += zs[1*768+d]*xv.x + zs[1*768+d+1]*xv.y + zs[1*768+d+2]*xv.z + zs[1*768+d+3]*xv.w;
      a2 += zs[2*768+d]*xv.x + zs[2*768+d+1]*xv.y + zs[2*768+d+2]*xv.z + zs[2*768+d+3]*xv.w;
      a3 += zs[3*768+d]*xv.x + zs[3*768+d+1]*xv.y + zs[3*768+d+2]*xv.z + zs[3*768+d+3]*xv.w;
    }
    rs[0*NPP+tid]=a0; rs[1*NPP+tid]=a1; rs[2*NPP+tid]=a2; rs[3*NPP+tid]=a3;
  }
  __syncthreads();
  const int w = tid >> 6, lane = tid & 63;   // 4 waves, one concept row each
  {
    const int c = w;                          // local row 0..3
    float best = -1e30f; int bi = 0;
    #pragma unroll
    for (int q = 0; q < 4; ++q) {
      int p = lane + q*64;
      if (p < NPP) {
        float v = rs[c*NPP + p];
        if (v > best) { best = v; bi = p; }
      }
    }
    for (int off = 32; off; off >>= 1) {
      float ov = __shfl_xor(best, off);
      int   oi = __shfl_xor(bi, off);
      if (ov > best || (ov == best && oi < bi)) { best = ov; bi = oi; }
    }
    // faithful to reference: center (h = loc%14, w = loc//14) [transposed meshgrid]
    const float mx = (float)(bi % 14), my = (float)(bi / 14);
    #pragma unroll
    for (int q = 0; q < 4; ++q) {
      int p = lane + q*64;
      if (p < NPP) {
        float hh = (float)(p / 14), ww = (float)(p % 14);
        float d2 = (hh - mx)*(hh - mx) + (ww - my)*(ww - my);
        regm[((size_t)b*NCC + half*4 + c)*NPP + p] = rs[c*NPP + p] * __expf(-2.0f * d2);
      }
    }
  }
}

// ---------------- fused scores+mask+softmax v5: v4 + dead-row staging trim ------------------------
// Rows >= 205 of Ys/Xs are never staged (their stale/uninit LDS contents only feed fully-guarded
// dead rows/columns: MFMA is column-independent; softmax reductions never cross rows; all stores
// gated by gi<NT / c<NT). Saves 51 Y-rows + 3 X-rows of stage traffic per k0-iter.
__global__ __launch_bounds__(1024) void k_sms(const u16* __restrict__ yv, const u16* __restrict__ xb,
                                              const float* __restrict__ regm, float* __restrict__ S,
                                              u16* __restrict__ pb) {
  __shared__ u16 Ys[256*40];   // 20.5 KB
  __shared__ u16 Xs[208*40];   // 16.6 KB
  const int tid = threadIdx.x, wid = tid >> 6, lane = tid & 63;
  const int b = (blockIdx.x & 7) * 32 + (blockIdx.x >> 3);   // 256 blocks, XCD-chunked
  const int fr = lane & 15, fg = lane >> 4;
  const int sr3 = tid >> 2, sc3 = (tid & 3) * 8;             // stage: rows x 32 k-cols
  const size_t xbase = (size_t)b * NT;
  const u16* gy = yv + (xbase + (size_t)sr3) * LDY + sc3;    // valid only when sr3 < NT
  const u16* gx = xb + (xbase + (size_t)sr3) * DIMD + sc3;   // valid only when sr3 < NT
  f32x4 acc[13] = {};
  for (int k0 = 0; k0 < 768; k0 += 32) {
    if (sr3 < NT) {
      *(bf16x8*)&Ys[sr3*40 + sc3] = *(const bf16x8*)(gy + k0);
      *(bf16x8*)&Xs[sr3*40 + sc3] = *(const bf16x8*)(gx + k0);
    }
    __syncthreads();
    bf16x8 a = *(const bf16x8*)&Ys[(wid*16 + fr)*40 + fg*8];
    #pragma unroll
    for (int n = 0; n < 13; ++n) {
      bf16x8 bv = *(const bf16x8*)&Xs[(n*16 + fr)*40 + fg*8];
      acc[n] = mfma16(a, bv, acc[n]);
    }
    __syncthreads();
  }
  #pragma unroll
  for (int jj = 0; jj < 4; ++jj) {
    const int gi = wid*16 + fg*4 + jj;          // 0..255
    if (gi >= 197 && gi < NT) {                 // concept row: exact masked region, cols 1..196
      const float* rm = regm + ((size_t)b*NCC + (gi - 197)) * NPP;
      #pragma unroll
      for (int n = 0; n < 13; ++n) {
        int c = n*16 + fr;
        if (c >= 1 && c <= NPP) acc[n][jj] = rm[c - 1];
      }
    }
    float m = -1e30f;
    #pragma unroll
    for (int n = 0; n < 13; ++n) {
      int c = n*16 + fr;
      float v = (c < NT) ? acc[n][jj] * SCL : -1e30f;
      acc[n][jj] = v;
      m = fmaxf(m, v);
    }
    m = fmaxf(m, __shfl_xor(m, 1)); m = fmaxf(m, __shfl_xor(m, 2));
    m = fmaxf(m, __shfl_xor(m, 4)); m = fmaxf(m, __shfl_xor(m, 8));
    float s = 0.f;
    #pragma unroll
    for (int n = 0; n < 13; ++n) {
      int c = n*16 + fr;
      float e = (c < NT) ? __expf(acc[n][jj] - m) : 0.f;
      acc[n][jj] = e;
      s += e;
    }
    s += __shfl_xor(s, 1); s += __shfl_xor(s, 2);
    s += __shfl_xor(s, 4); s += __shfl_xor(s, 8);
    const float inv = 1.0f / s;
    if (gi < NT) {
      float* So = S + ((size_t)b*NT + gi) * NT;
      u16*   pr = pb + ((size_t)b*NT + gi) * 256;
      #pragma unroll
      for (int n = 0; n < 13; ++n) {
        int c = n*16 + fr;
        if (c < NT) So[c] = acc[n][jj] * inv;
      }
      #pragma unroll
      for (int n = 0; n < 16; ++n) {
        int c = n*16 + fr;
        u16 v = 0;
        if (n < 13 && c < NT) v = f2bf(acc[n][jj] * inv);
        pr[c] = v;
      }
    }
  }
}

// ---------------- batched PV v6 (round-17 verified): one block per (batch, e-tile) ---------------
__global__ __launch_bounds__(256) void k_pv(const u16* __restrict__ pb, const u16* __restrict__ yv,
                                            float* __restrict__ out) {
  __shared__ u16 Ps[64*232];    // [i-row][k], stride 232 (restaged per i-tile)
  __shared__ u16 Vt_s[64*232];  // [e][k] transposed, k XOR-swizzled per 32-chunk (staged once)
  const int tid = threadIdx.x, wid = tid >> 6, lane = tid & 63;
  const int swz = (blockIdx.x & 7) * 384 + (blockIdx.x >> 3);   // 3072 = 8 * 384
  const int b = swz / 12, e0 = (swz % 12) * 64;
  const int wr = (wid >> 1) * 32, wc = (wid & 1) * 32;
  const int fr = lane & 15, fg = lane >> 4;
  {
    const int vr = tid >> 3, g = tid & 7;
    const int vks = vr ^ ((g & 3) << 3);
    #pragma unroll
    for (int c = 0; c < 7; ++c) {
      const int kv = min(c*32 + vr, NT-1);
      bf16x8 vv = *(const bf16x8*)&yv[((size_t)b*NT + kv)*LDY + 768 + e0 + g*8];
      #pragma unroll
      for (int j = 0; j < 8; ++j) Vt_s[(g*8 + j)*232 + c*32 + vks] = (u16)vv[j];
    }
  }
  const int er0 = wc + fr, er1 = wc + 16 + fr;
  const int kx0 = (fg*8) ^ (((er0 >> 3) & 3) << 3);
  const int kx1 = (fg*8) ^ (((er1 >> 3) & 3) << 3);
  const int sr = tid >> 2, cb = (tid & 3) * 8;
  for (int it = 0; it < 4; ++it) {
    const int i0 = it * 64;
    {
      const int ip = min(i0 + sr, NT-1);
      const u16* Pp = pb + ((size_t)b*NT + ip) * 256;
      #pragma unroll
      for (int j = 0; j < 7; ++j) {
        const int col = cb + 32*j;
        *(bf16x8*)&Ps[sr*232 + col] = *(const bf16x8*)&Pp[col];
      }
    }
    __syncthreads();
    f32x4 acc[2][2] = {};
    #pragma unroll
    for (int k = 0; k < 7; ++k) {
      bf16x8 av[2], bv[2];
      av[0] = *(const bf16x8*)&Ps[(wr      + fr)*232 + k*32 + fg*8];
      av[1] = *(const bf16x8*)&Ps[(wr + 16 + fr)*232 + k*32 + fg*8];
      bv[0] = *(const bf16x8*)&Vt_s[er0*232 + k*32 + kx0];
      bv[1] = *(const bf16x8*)&Vt_s[er1*232 + k*32 + kx1];
      acc[0][0] = mfma16(av[0], bv[0], acc[0][0]);
      acc[0][1] = mfma16(av[0], bv[1], acc[0][1]);
      acc[1][0] = mfma16(av[1], bv[0], acc[1][0]);
      acc[1][1] = mfma16(av[1], bv[1], acc[1][1]);
    }
    #pragma unroll
    for (int m = 0; m < 2; ++m)
      #pragma unroll
      for (int n = 0; n < 2; ++n)
        #pragma unroll
        for (int j = 0; j < 4; ++j) {
          int i = i0 + wr + m*16 + fg*4 + j;
          int e = e0 + wc + n*16 + fr;
          if (i < NT)
            out[((size_t)b*NT + i)*DIMD + e] = acc[m][n][j];
        }
    __syncthreads();
  }
}

extern "C" void kernel_launch(void* const* d_in, const int* in_sizes, int n_in,
                              void* d_out, int out_size, void* d_ws, size_t ws_size,
                              hipStream_t stream) {
  const float* x  = (const float*)d_in[0];
  const float* Wq = (const float*)d_in[1];
  const float* Wk = (const float*)d_in[2];
  const float* Wv = (const float*)d_in[3];
  char* ws = (char*)d_ws;
  char* ob = (char*)d_out;

  u16*   wb   = (u16*)(ws + WS_WB);     // [1536][768] bf16: Mt | Wv
  u16*   yv   = (u16*)(ws + WS_YV);     // [52480][1536] bf16 (Y | V), live until k_pv done
  u16*   pb   = (u16*)(ws + WS_PB);     // [52480][256] bf16 padded probs

  float* S    = (float*)ob;             // [256][205][205] final attn probs
  float* outp = (float*)(ob + DO_OUT);  // [256][205][768] final output
  u16*   xb   = (u16*)(ob + DO_XB);     // bf16 x (live until k_sms done)
  float* Mt   = (float*)(ob + DO_M);    // [768][768] fp32 Wk^T*Wq = M^T
  float* zz   = (float*)(ob + DO_Z);    // [2048][768] fp32 Xc*M
  float* regm = (float*)(ob + DO_REGM); // [2048][196] fp32 masked region values

  // L1: Mt = Wk^T*Wq (144 blocks, starts early) || casts x->xb, Wv->wb V-half
  k_L1<<<20112, 256, 0, stream>>>(Wk, Wq, Mt, wb, x, xb, Wv, wb + 589824);
  // zz = Xc*M (standalone; round-12: fusing into MFMA kernel inflates VGPR)
  k_zz<<<384, 256, 0, stream>>>(x, Mt, zz);
  // Y|V GEMM (bf16 MFMA), round-6 form (do not modify)
  k_yv<<<4920, 256, 0, stream>>>(xb, wb, yv);
  // fused region+argmax+mask v2 (2 blocks/batch, fp32 exact)
  k_regmask<<<512, 256, 0, stream>>>(zz, x, regm);
  // fused scores+mask+softmax v5 (dead-row stage trim) -> S + bf16 padded probs pb
  k_sms<<<256, 1024, 0, stream>>>(yv, xb, regm, S, pb);
  // PV v6 -> final out region (one block per (b, e-tile), V staged once)
  k_pv<<<3072, 256, 0, stream>>>(pb, yv, outp);
}

// Round 20
// 483.817 us; speedup vs baseline: 1.0517x; 1.0517x over previous
//
#include <hip/hip_runtime.h>
#include <hip/hip_bf16.h>

// ---------------- problem constants ----------------
#define NB   256        // batch
#define NT   205        // tokens per batch (1 CLS + 196 patches + 8 concept)
#define DIMD 768
#define NCC  8
#define NPP  196
#define LDY  1536       // yv row stride (Y | V concatenated)
#define SCL  0.03608439182435161f   // 768^-0.5

using u16 = unsigned short;
using u32 = unsigned int;
using bf16x8 = __attribute__((ext_vector_type(8))) short;
using f32x4  = __attribute__((ext_vector_type(4))) float;

// ---------------- buffer byte offsets ----------------
// d_ws:  wb[1536x768 bf16] | yv[52480x1536 bf16] | pb[52480x256 bf16]
//   wb:  [0, 2359296)   yv: [3538944, 164757504)   pb: [164757504, 191627264) < safe 245366784.
#define WS_WB   0ul
#define WS_YV   3538944ul
#define WS_PB   164757504ul
// d_out: [0,43033600) = attn fp32 (final, k_sms). [43033600,204129280) = out fp32 (final, k_pv).
//        Temporaries in the tail (all dead before k_pv writes):
//          xb bf16 x [52480x768]  (live until k_sms)      @ +43033600  (ends 123,642,880)
//          Mt fp32 [768x768] = Wk^T*Wq = M^T              @ +143696896
//          zz fp32 [2048x768]                             @ +149988352
//          regm fp32 [2048x196] masked region values      @ +157885440 (ends 159,491,072)
#define DO_OUT  43033600ul
#define DO_XB   43033600ul
#define DO_M    143696896ul
#define DO_Z    149988352ul
#define DO_REGM 157885440ul

__device__ __forceinline__ u16 f2bf(float f) {
  u32 u = __float_as_uint(f);
  u += 0x7FFFu + ((u >> 16) & 1u);
  return (u16)(u >> 16);
}

__device__ __forceinline__ void gld16(const void* g, void* l) {
  __builtin_amdgcn_global_load_lds((const __attribute__((address_space(1))) u32*)g,
                                   (__attribute__((address_space(3))) u32*)l, 16, 0, 0);
}

__device__ __forceinline__ f32x4 mfma16(bf16x8 a, bf16x8 b, f32x4 c) {
  return __builtin_amdgcn_mfma_f32_16x16x32_bf16(a, b, c, 0, 0, 0);
}

// ---------------- device fn: fp32 -> bf16 cast body, 8 elems per slot ----------------
__device__ __forceinline__ void dev_cast(const float* __restrict__ s, u16* __restrict__ d, int i, int n8) {
  if (i >= n8) return;
  const float4* s4 = (const float4*)s;
  float4 a = s4[2*(size_t)i], b = s4[2*(size_t)i + 1];
  union { u16 h[8]; uint4 v; } r;
  r.h[0]=f2bf(a.x); r.h[1]=f2bf(a.y); r.h[2]=f2bf(a.z); r.h[3]=f2bf(a.w);
  r.h[4]=f2bf(b.x); r.h[5]=f2bf(b.y); r.h[6]=f2bf(b.z); r.h[7]=f2bf(b.w);
  *(uint4*)(d + 8*(size_t)i) = r.v;
}

// ---------------- device fn: fp32 tiled GEMM (64x64 tile, 4x4/thread) ----------------
// AM: 0 = A [M,K]; 1 = A [K,M] (transposed); 2 = [M,K] with concept-row gather.
// BT: B [N,K] if true else [K,N].  CB: also emit bf16 copy of C into Cb.
template<int AM, bool BT, bool CB>
__device__ void dev_gemm32(const float* __restrict__ A, const float* __restrict__ Bm,
                           float* __restrict__ C, u16* __restrict__ Cb,
                           int lda, int ldb, int ldc, int K, int nbn, int bid) {
  __shared__ float As[16][68];
  __shared__ float Bs[16][68];
  const int tid = threadIdx.x;
  const int m0 = (bid / nbn) * 64, n0 = (bid % nbn) * 64;
  const int ty = tid >> 4, tx = tid & 15;
  const int sr = tid >> 2, sk = (tid & 3) * 4;
  float acc[4][4] = {};
  for (int k0 = 0; k0 < K; k0 += 16) {
    if (AM == 1) {
      const int ak = tid >> 4, am = (tid & 15) * 4;
      float4 av = *(const float4*)&A[(size_t)(k0 + ak) * lda + m0 + am];
      *(float4*)&As[ak][am] = av;
    } else {
      size_t arow = (size_t)(m0 + sr);
      if (AM == 2) arow = (arow >> 3) * 205 + 197 + (arow & 7);
      float4 av = *(const float4*)&A[arow * lda + k0 + sk];
      As[sk+0][sr] = av.x; As[sk+1][sr] = av.y; As[sk+2][sr] = av.z; As[sk+3][sr] = av.w;
    }
    if (BT) {
      float4 bv = *(const float4*)&Bm[(size_t)(n0 + sr) * ldb + k0 + sk];
      Bs[sk+0][sr] = bv.x; Bs[sk+1][sr] = bv.y; Bs[sk+2][sr] = bv.z; Bs[sk+3][sr] = bv.w;
    } else {
      const int bk = tid >> 4, bn4 = (tid & 15) * 4;
      float4 bv = *(const float4*)&Bm[(size_t)(k0 + bk) * ldb + n0 + bn4];
      *(float4*)&Bs[bk][bn4] = bv;
    }
    __syncthreads();
    #pragma unroll
    for (int kk = 0; kk < 16; ++kk) {
      float4 a4 = *(const float4*)&As[kk][ty*4];
      float4 b4 = *(const float4*)&Bs[kk][tx*4];
      float a[4] = {a4.x, a4.y, a4.z, a4.w};
      float b[4] = {b4.x, b4.y, b4.z, b4.w};
      #pragma unroll
      for (int i = 0; i < 4; ++i)
        #pragma unroll
        for (int j = 0; j < 4; ++j) acc[i][j] += a[i]*b[j];
    }
    __syncthreads();
  }
  #pragma unroll
  for (int i = 0; i < 4; ++i) {
    float4 o = {acc[i][0], acc[i][1], acc[i][2], acc[i][3]};
    *(float4*)&C[(size_t)(m0 + ty*4 + i) * ldc + n0 + tx*4] = o;
    if (CB) {
      union { u16 h[4]; uint2 v; } w;
      w.h[0] = f2bf(o.x); w.h[1] = f2bf(o.y); w.h[2] = f2bf(o.z); w.h[3] = f2bf(o.w);
      *(uint2*)&Cb[(size_t)(m0 + ty*4 + i) * ldc + n0 + tx*4] = w.v;
    }
  }
}

// ---------------- fused launch 1: blocks [0,144) = Mt GEMM (+bf16 copy); rest = casts -------------
#define NGX 5038080   // x groups of 8
#define NGW 73728     // Wv groups of 8
__global__ __launch_bounds__(256) void k_L1(const float* __restrict__ Wk, const float* __restrict__ Wq,
                                            float* __restrict__ Mt, u16* __restrict__ wb,
                                            const float* __restrict__ x, u16* __restrict__ xb,
                                            const float* __restrict__ wv, u16* __restrict__ wbv) {
  const int bid = blockIdx.x;
  if (bid < 144) {
    dev_gemm32<1, false, true>(Wk, Wq, Mt, wb, 768, 768, 768, 768, 12, bid);
  } else {
    int i = (bid - 144) * 256 + threadIdx.x;
    if (i < NGX) dev_cast(x, xb, i, NGX);
    else dev_cast(wv, wbv, i - NGX, NGW);
  }
}

// ---------------- standalone zz GEMM (round-12 lesson: never fuse into the MFMA kernel) -----------
__global__ __launch_bounds__(256) void k_zz(const float* __restrict__ x, const float* __restrict__ Mt,
                                            float* __restrict__ zz) {
  dev_gemm32<2, true, false>(x, Mt, zz, nullptr, 768, 768, 768, 768, 12, blockIdx.x);
}

// ---------------- big Y|V GEMM: round-6 form, byte-identical (measured 9x at 188-192us, VGPR 68).
// DO NOT MODIFY (r7/r12/r14 structural attempts all regressed).
__global__ __launch_bounds__(256) void k_yv(const u16* __restrict__ A, const u16* __restrict__ Bt, u16* __restrict__ C) {
  __shared__ u16 As[128*32];
  __shared__ u16 Bs[128*32];
  const int tid = threadIdx.x, wid = tid >> 6, lane = tid & 63;
  const int swz = (blockIdx.x & 7) * 615 + (blockIdx.x >> 3);
  const int bm = swz / 12, bn = swz % 12;
  const size_t m0 = (size_t)bm * 128;
  const int n0 = bn * 128;
  const int wr = (wid >> 1) * 64, wc = (wid & 1) * 64;
  const int fr = lane & 15, fg = lane >> 4;
  const int eb0 = (wid*2+0)*512, eb1 = (wid*2+1)*512;
  const int e0 = eb0 + lane*8, e1 = eb1 + lane*8;
  const int r0 = e0 >> 5, c0 = e0 & 31, r1 = e1 >> 5, c1 = e1 & 31;
  f32x4 acc[4][4] = {};
  for (int k0 = 0; k0 < 768; k0 += 32) {
    gld16(A + (m0 + r0)*768 + k0 + c0, (char*)As + 2*eb0);
    gld16(A + (m0 + r1)*768 + k0 + c1, (char*)As + 2*eb1);
    gld16(Bt + (size_t)(n0 + r0)*768 + k0 + c0, (char*)Bs + 2*eb0);
    gld16(Bt + (size_t)(n0 + r1)*768 + k0 + c1, (char*)Bs + 2*eb1);
    __syncthreads();
    bf16x8 av[4], bv[4];
    #pragma unroll
    for (int m = 0; m < 4; ++m) av[m] = *(const bf16x8*)&As[(wr + m*16 + fr)*32 + fg*8];
    #pragma unroll
    for (int n = 0; n < 4; ++n) bv[n] = *(const bf16x8*)&Bs[(wc + n*16 + fr)*32 + fg*8];
    #pragma unroll
    for (int m = 0; m < 4; ++m)
      #pragma unroll
      for (int n = 0; n < 4; ++n)
        acc[m][n] = mfma16(av[m], bv[n], acc[m][n]);
    __syncthreads();
  }
  #pragma unroll
  for (int m = 0; m < 4; ++m) {
    #pragma unroll
    for (int j = 0; j < 4; ++j) {
      size_t row = m0 + wr + m*16 + fg*4 + j;
      u16* cp = C + row*LDY + n0 + wc;
      #pragma unroll
      for (int n = 0; n < 4; ++n) cp[n*16 + fr] = f2bf(acc[m][n][j]);
    }
  }
}

// ---------------- fused region + argmax + gaussian mask v1 (round-18 verified): 1 block/batch ------
// (v2 2-block split regressed +~12us: doubled the x-panel reads — the kernel is read-bound.)
__global__ __launch_bounds__(256) void k_regmask(const float* __restrict__ zz, const float* __restrict__ x,
                                                 float* __restrict__ regm) {
  const int b = blockIdx.x, tid = threadIdx.x;
  __shared__ float zs[8*768];   // 24 KB
  __shared__ float rs[8*NPP];   // 6.3 KB
  for (int idx = tid; idx < 8*768; idx += 256) zs[idx] = zz[(size_t)b*8*768 + idx];
  __syncthreads();
  if (tid < NPP) {
    const float* xp = x + ((size_t)b*NT + 1 + tid) * DIMD;
    float a0=0,a1=0,a2=0,a3=0,a4=0,a5=0,a6=0,a7=0;
    #pragma unroll 4
    for (int d = 0; d < 768; d += 4) {
      float4 xv = *(const float4*)&xp[d];
      a0 += zs[0*768+d]*xv.x + zs[0*768+d+1]*xv.y + zs[0*768+d+2]*xv.z + zs[0*768+d+3]*xv.w;
      a1 += zs[1*768+d]*xv.x + zs[1*768+d+1]*xv.y + zs[1*768+d+2]*xv.z + zs[1*768+d+3]*xv.w;
      a2 += zs[2*768+d]*xv.x + zs[2*768+d+1]*xv.y + zs[2*768+d+2]*xv.z + zs[2*768+d+3]*xv.w;
      a3 += zs[3*768+d]*xv.x + zs[3*768+d+1]*xv.y + zs[3*768+d+2]*xv.z + zs[3*768+d+3]*xv.w;
      a4 += zs[4*768+d]*xv.x + zs[4*768+d+1]*xv.y + zs[4*768+d+2]*xv.z + zs[4*768+d+3]*xv.w;
      a5 += zs[5*768+d]*xv.x + zs[5*768+d+1]*xv.y + zs[5*768+d+2]*xv.z + zs[5*768+d+3]*xv.w;
      a6 += zs[6*768+d]*xv.x + zs[6*768+d+1]*xv.y + zs[6*768+d+2]*xv.z + zs[6*768+d+3]*xv.w;
      a7 += zs[7*768+d]*xv.x + zs[7*768+d+1]*xv.y + zs[7*768+d+2]*xv.z + zs[7*768+d+3]*xv.w;
    }
    rs[0*NPP+tid]=a0; rs[1*NPP+tid]=a1; rs[2*NPP+tid]=a2; rs[3*NPP+tid]=a3;
    rs[4*NPP+tid]=a4; rs[5*NPP+tid]=a5; rs[6*NPP+tid]=a6; rs[7*NPP+tid]=a7;
  }
  __syncthreads();
  const int w = tid >> 6, lane = tid & 63;
  #pragma unroll
  for (int cc = 0; cc < 2; ++cc) {
    const int c = 2*w + cc;
    float best = -1e30f; int bi = 0;
    #pragma unroll
    for (int q = 0; q < 4; ++q) {
      int p = lane + q*64;
      if (p < NPP) {
        float v = rs[c*NPP + p];
        if (v > best) { best = v; bi = p; }
      }
    }
    for (int off = 32; off; off >>= 1) {
      float ov = __shfl_xor(best, off);
      int   oi = __shfl_xor(bi, off);
      if (ov > best || (ov == best && oi < bi)) { best = ov; bi = oi; }
    }
    // faithful to reference: center (h = loc%14, w = loc//14) [transposed meshgrid]
    const float mx = (float)(bi % 14), my = (float)(bi / 14);
    #pragma unroll
    for (int q = 0; q < 4; ++q) {
      int p = lane + q*64;
      if (p < NPP) {
        float hh = (float)(p / 14), ww = (float)(p % 14);
        float d2 = (hh - mx)*(hh - mx) + (ww - my)*(ww - my);
        regm[((size_t)b*NCC + c)*NPP + p] = rs[c*NPP + p] * __expf(-2.0f * d2);
      }
    }
  }
}

// ---------------- fused scores+mask+softmax v4 (round-18 verified): 1024-thr block per batch ------
// (v5 dead-row trim regressed: the per-iter staging branch de-clustered the loads.)
__global__ __launch_bounds__(1024) void k_sms(const u16* __restrict__ yv, const u16* __restrict__ xb,
                                              const float* __restrict__ regm, float* __restrict__ S,
                                              u16* __restrict__ pb) {
  __shared__ u16 Ys[256*40];   // 20.5 KB
  __shared__ u16 Xs[208*40];   // 16.6 KB
  const int tid = threadIdx.x, wid = tid >> 6, lane = tid & 63;
  const int b = (blockIdx.x & 7) * 32 + (blockIdx.x >> 3);   // 256 blocks, XCD-chunked
  const int fr = lane & 15, fg = lane >> 4;
  const int sr3 = tid >> 2, sc3 = (tid & 3) * 8;             // stage: 256 rows x 32 k-cols
  const size_t xbase = (size_t)b * NT;
  const int rcl = min(sr3, NT-1);
  const u16* gy = yv + (xbase + (size_t)rcl) * LDY + sc3;
  const u16* gx = xb + (xbase + (size_t)rcl) * DIMD + sc3;   // used only when sr3 < 208
  f32x4 acc[13] = {};
  for (int k0 = 0; k0 < 768; k0 += 32) {
    *(bf16x8*)&Ys[sr3*40 + sc3] = *(const bf16x8*)(gy + k0);
    if (sr3 < 208)
      *(bf16x8*)&Xs[sr3*40 + sc3] = *(const bf16x8*)(gx + k0);
    __syncthreads();
    bf16x8 a = *(const bf16x8*)&Ys[(wid*16 + fr)*40 + fg*8];
    #pragma unroll
    for (int n = 0; n < 13; ++n) {
      bf16x8 bv = *(const bf16x8*)&Xs[(n*16 + fr)*40 + fg*8];
      acc[n] = mfma16(a, bv, acc[n]);
    }
    __syncthreads();
  }
  #pragma unroll
  for (int jj = 0; jj < 4; ++jj) {
    const int gi = wid*16 + fg*4 + jj;          // 0..255
    if (gi >= 197 && gi < NT) {                 // concept row: exact masked region, cols 1..196
      const float* rm = regm + ((size_t)b*NCC + (gi - 197)) * NPP;
      #pragma unroll
      for (int n = 0; n < 13; ++n) {
        int c = n*16 + fr;
        if (c >= 1 && c <= NPP) acc[n][jj] = rm[c - 1];
      }
    }
    float m = -1e30f;
    #pragma unroll
    for (int n = 0; n < 13; ++n) {
      int c = n*16 + fr;
      float v = (c < NT) ? acc[n][jj] * SCL : -1e30f;
      acc[n][jj] = v;
      m = fmaxf(m, v);
    }
    m = fmaxf(m, __shfl_xor(m, 1)); m = fmaxf(m, __shfl_xor(m, 2));
    m = fmaxf(m, __shfl_xor(m, 4)); m = fmaxf(m, __shfl_xor(m, 8));
    float s = 0.f;
    #pragma unroll
    for (int n = 0; n < 13; ++n) {
      int c = n*16 + fr;
      float e = (c < NT) ? __expf(acc[n][jj] - m) : 0.f;
      acc[n][jj] = e;
      s += e;
    }
    s += __shfl_xor(s, 1); s += __shfl_xor(s, 2);
    s += __shfl_xor(s, 4); s += __shfl_xor(s, 8);
    const float inv = 1.0f / s;
    if (gi < NT) {
      float* So = S + ((size_t)b*NT + gi) * NT;
      u16*   pr = pb + ((size_t)b*NT + gi) * 256;
      #pragma unroll
      for (int n = 0; n < 13; ++n) {
        int c = n*16 + fr;
        if (c < NT) So[c] = acc[n][jj] * inv;
      }
      #pragma unroll
      for (int n = 0; n < 16; ++n) {
        int c = n*16 + fr;
        u16 v = 0;
        if (n < 13 && c < NT) v = f2bf(acc[n][jj] * inv);
        pr[c] = v;
      }
    }
  }
}

// ---------------- batched PV v6 (round-17 verified): one block per (batch, e-tile) ---------------
__global__ __launch_bounds__(256) void k_pv(const u16* __restrict__ pb, const u16* __restrict__ yv,
                                            float* __restrict__ out) {
  __shared__ u16 Ps[64*232];    // [i-row][k], stride 232 (restaged per i-tile)
  __shared__ u16 Vt_s[64*232];  // [e][k] transposed, k XOR-swizzled per 32-chunk (staged once)
  const int tid = threadIdx.x, wid = tid >> 6, lane = tid & 63;
  const int swz = (blockIdx.x & 7) * 384 + (blockIdx.x >> 3);   // 3072 = 8 * 384
  const int b = swz / 12, e0 = (swz % 12) * 64;
  const int wr = (wid >> 1) * 32, wc = (wid & 1) * 32;
  const int fr = lane & 15, fg = lane >> 4;
  {
    const int vr = tid >> 3, g = tid & 7;
    const int vks = vr ^ ((g & 3) << 3);
    #pragma unroll
    for (int c = 0; c < 7; ++c) {
      const int kv = min(c*32 + vr, NT-1);
      bf16x8 vv = *(const bf16x8*)&yv[((size_t)b*NT + kv)*LDY + 768 + e0 + g*8];
      #pragma unroll
      for (int j = 0; j < 8; ++j) Vt_s[(g*8 + j)*232 + c*32 + vks] = (u16)vv[j];
    }
  }
  const int er0 = wc + fr, er1 = wc + 16 + fr;
  const int kx0 = (fg*8) ^ (((er0 >> 3) & 3) << 3);
  const int kx1 = (fg*8) ^ (((er1 >> 3) & 3) << 3);
  const int sr = tid >> 2, cb = (tid & 3) * 8;
  for (int it = 0; it < 4; ++it) {
    const int i0 = it * 64;
    {
      const int ip = min(i0 + sr, NT-1);
      const u16* Pp = pb + ((size_t)b*NT + ip) * 256;
      #pragma unroll
      for (int j = 0; j < 7; ++j) {
        const int col = cb + 32*j;
        *(bf16x8*)&Ps[sr*232 + col] = *(const bf16x8*)&Pp[col];
      }
    }
    __syncthreads();
    f32x4 acc[2][2] = {};
    #pragma unroll
    for (int k = 0; k < 7; ++k) {
      bf16x8 av[2], bv[2];
      av[0] = *(const bf16x8*)&Ps[(wr      + fr)*232 + k*32 + fg*8];
      av[1] = *(const bf16x8*)&Ps[(wr + 16 + fr)*232 + k*32 + fg*8];
      bv[0] = *(const bf16x8*)&Vt_s[er0*232 + k*32 + kx0];
      bv[1] = *(const bf16x8*)&Vt_s[er1*232 + k*32 + kx1];
      acc[0][0] = mfma16(av[0], bv[0], acc[0][0]);
      acc[0][1] = mfma16(av[0], bv[1], acc[0][1]);
      acc[1][0] = mfma16(av[1], bv[0], acc[1][0]);
      acc[1][1] = mfma16(av[1], bv[1], acc[1][1]);
    }
    #pragma unroll
    for (int m = 0; m < 2; ++m)
      #pragma unroll
      for (int n = 0; n < 2; ++n)
        #pragma unroll
        for (int j = 0; j < 4; ++j) {
          int i = i0 + wr + m*16 + fg*4 + j;
          int e = e0 + wc + n*16 + fr;
          if (i < NT)
            out[((size_t)b*NT + i)*DIMD + e] = acc[m][n][j];
        }
    __syncthreads();
  }
}

extern "C" void kernel_launch(void* const* d_in, const int* in_sizes, int n_in,
                              void* d_out, int out_size, void* d_ws, size_t ws_size,
                              hipStream_t stream) {
  const float* x  = (const float*)d_in[0];
  const float* Wq = (const float*)d_in[1];
  const float* Wk = (const float*)d_in[2];
  const float* Wv = (const float*)d_in[3];
  char* ws = (char*)d_ws;
  char* ob = (char*)d_out;

  u16*   wb   = (u16*)(ws + WS_WB);     // [1536][768] bf16: Mt | Wv
  u16*   yv   = (u16*)(ws + WS_YV);     // [52480][1536] bf16 (Y | V), live until k_pv done
  u16*   pb   = (u16*)(ws + WS_PB);     // [52480][256] bf16 padded probs

  float* S    = (float*)ob;             // [256][205][205] final attn probs
  float* outp = (float*)(ob + DO_OUT);  // [256][205][768] final output
  u16*   xb   = (u16*)(ob + DO_XB);     // bf16 x (live until k_sms done)
  float* Mt   = (float*)(ob + DO_M);    // [768][768] fp32 Wk^T*Wq = M^T
  float* zz   = (float*)(ob + DO_Z);    // [2048][768] fp32 Xc*M
  float* regm = (float*)(ob + DO_REGM); // [2048][196] fp32 masked region values

  // L1: Mt = Wk^T*Wq (144 blocks, starts early) || casts x->xb, Wv->wb V-half
  k_L1<<<20112, 256, 0, stream>>>(Wk, Wq, Mt, wb, x, xb, Wv, wb + 589824);
  // zz = Xc*M (standalone; round-12: fusing into MFMA kernel inflates VGPR)
  k_zz<<<384, 256, 0, stream>>>(x, Mt, zz);
  // Y|V GEMM (bf16 MFMA), round-6 form (do not modify)
  k_yv<<<4920, 256, 0, stream>>>(xb, wb, yv);
  // fused region+argmax+mask v1 (1 block/batch, fp32 exact)
  k_regmask<<<256, 256, 0, stream>>>(zz, x, regm);
  // fused scores+mask+softmax v4 (one 1024-thr block/batch) -> S + bf16 padded probs pb
  k_sms<<<256, 1024, 0, stream>>>(yv, xb, regm, S, pb);
  // PV v6 -> final out region (one block per (b, e-tile), V staged once)
  k_pv<<<3072, 256, 0, stream>>>(pb, yv, outp);
}